// Round 2
// baseline (262.574 us; speedup 1.0000x reference)
//
#include <hip/hip_runtime.h>

#define T_TOTAL 200000
#define BATCH 256
#define NBIT 64
#define NCLASS 100
#define TN 128
#define NBLK ((T_TOTAL + TN - 1) / TN)   // 1563

typedef __attribute__((ext_vector_type(8))) short bf16x8;
typedef __attribute__((ext_vector_type(4))) float f32x4;

#define LOG2E 1.4426950408889634f
#define LN2   0.6931471805599453

__device__ __forceinline__ unsigned short f2bf(float v) {
    union { float f; unsigned int u; } x; x.f = v;
    unsigned int r = x.u + 0x7fffu + ((x.u >> 16) & 1u);   // RNE to bf16
    return (unsigned short)(r >> 16);
}

__device__ __forceinline__ float sgnf(float v) {
    return (v > 0.f) ? 1.f : ((v < 0.f) ? -1.f : 0.f);
}

// ---------------- kernel A: batch labels + zero metric accumulator -----------
__global__ __launch_bounds__(256) void prep_kernel(const float* __restrict__ y,
                                                   int* __restrict__ lab,
                                                   double* __restrict__ acc) {
    int idx = blockIdx.x * 256 + threadIdx.x;
    if (idx == 0) acc[0] = 0.0;
    if (idx < BATCH * NCLASS) {
        float v = y[idx];
        if (v > 0.5f) lab[idx / NCLASS] = idx % NCLASS;   // exactly one per row
    }
}

// ---------------- kernel B: DCC center update + quantization loss ------------
__global__ __launch_bounds__(256) void dcc_kernel(const float* __restrict__ u,
                                                  const float* __restrict__ C,
                                                  const int* __restrict__ lab,
                                                  float* __restrict__ out_c,   // d_out+1
                                                  float* __restrict__ quant_out) {
    __shared__ float Q[NCLASS][NBIT];    // 25.6 KB
    __shared__ float Ct[NCLASS][NBIT];   // 25.6 KB
    __shared__ float wq[4];

    const int tid = threadIdx.x;
    const int k   = tid & 63;
    const int g   = tid >> 6;            // 0..3 (wave id)

    for (int o = tid; o < NCLASS * NBIT; o += 256) {
        ((float*)Q)[o] = 0.f;
        int i = o >> 6, kk = o & 63;                 // o = i*64 + kk
        Ct[i][kk] = C[kk * NCLASS + i];
    }
    __syncthreads();

    // Q[i][k] = sum_{j: lab_j==i} b[k][j];  quant = sum (b - u)^2
    float qloc = 0.f;
    for (int jj = 0; jj < 64; ++jj) {
        int j = g * 64 + jj;
        int lj = lab[j];
        float uu = u[j * NBIT + k];
        float b = sgnf(C[k * NCLASS + lj] + uu);     // MU = 1
        atomicAdd(&Q[lj][k], b);                     // exact small ints: order-independent
        float d = b - uu;
        qloc += d * d;
    }
    // reduce quant
    for (int off = 32; off; off >>= 1) qloc += __shfl_xor(qloc, off);
    if ((tid & 63) == 0) wq[g] = qloc;
    __syncthreads();
    if (tid == 0) quant_out[0] = wq[0] + wq[1] + wq[2] + wq[3];

    // sequential cyclic coordinate descent (wave 0 only); G off-diag == 0 (one-hot)
    if (tid < 64) {
        float total = 0.f;
        for (int i = 0; i < NCLASS; ++i) total += Ct[i][k];
        for (int i = 0; i < NCLASS; ++i) {
            float old = Ct[i][k];
            float v = Q[i][k] - (total - old);       // VUL = 1
            float nr = sgnf(v);                     // exact: can be 0.0
            Ct[i][k] = nr;
            total += nr - old;
        }
    }
    __syncthreads();
    // C_new[k][i] = Ct[i][k]
    for (int o = tid; o < NCLASS * NBIT; o += 256) {
        int kk = o / NCLASS, i = o - kk * NCLASS;
        out_c[o] = Ct[i][kk];
    }
}

// ---------------- kernel C: metric loss (bf16 MFMA, fused softplus) ----------
__global__ __launch_bounds__(256) void metric_kernel(const float* __restrict__ u,
                                                     const float* __restrict__ U,
                                                     const float* __restrict__ Y,
                                                     const int* __restrict__ ind,
                                                     const int* __restrict__ lab,
                                                     double* __restrict__ acc) {
    __shared__ unsigned short Bt[TN][72];   // [col][k], pitch 72 shorts (144B, 16B-aligned)
    __shared__ int   labT[TN];
    __shared__ float labP[2][TN];
    __shared__ int   labB[BATCH];
    __shared__ float wpart[4];

    const int tid = threadIdx.x;
    const long t0 = (long)blockIdx.x * TN;

    labB[tid] = lab[tid];

    // ---- stage U tile (bf16, transposed) + label scan of Y ----
    {
        const int c = tid & 127;
        const int h = tid >> 7;                     // 0..1
        const long t = t0 + c;
        const bool ok = (t < (long)T_TOTAL);
        #pragma unroll
        for (int gg = 0; gg < 4; ++gg) {
            const int k0 = h * 32 + gg * 8;
            unsigned int w[4];
            #pragma unroll
            for (int p = 0; p < 4; ++p) {
                float v0 = 0.f, v1 = 0.f;
                if (ok) {
                    v0 = U[(long)(k0 + 2 * p) * T_TOTAL + t];
                    v1 = U[(long)(k0 + 2 * p + 1) * T_TOTAL + t];
                }
                w[p] = (unsigned int)f2bf(v0) | ((unsigned int)f2bf(v1) << 16);
            }
            uint4 q = make_uint4(w[0], w[1], w[2], w[3]);
            *reinterpret_cast<uint4*>(&Bt[c][k0]) = q;
        }
        float lp = 0.f;
        if (ok) {
            for (int r = 0; r < 50; ++r) {
                int row = h * 50 + r;
                lp = fmaf(Y[(long)row * T_TOTAL + t], (float)row, lp);
            }
        }
        labP[h][c] = lp;
    }
    __syncthreads();
    if (tid < TN) {
        long t = t0 + tid;
        labT[tid] = (t < (long)T_TOTAL) ? (int)(labP[0][tid] + labP[1][tid]) : -1;
    }
    __syncthreads();
    // ---- overwrite replaced columns (U_new / Y_new at ind; ind unique) ----
    {
        long t = (long)ind[tid];
        long c = t - t0;
        if (c >= 0 && c < TN) {
            labT[c] = labB[tid];
            #pragma unroll
            for (int gg = 0; gg < 8; ++gg) {
                const int k0 = gg * 8;
                unsigned int w[4];
                #pragma unroll
                for (int p = 0; p < 4; ++p) {
                    float v0 = u[tid * NBIT + k0 + 2 * p];
                    float v1 = u[tid * NBIT + k0 + 2 * p + 1];
                    w[p] = (unsigned int)f2bf(v0) | ((unsigned int)f2bf(v1) << 16);
                }
                *reinterpret_cast<uint4*>(&Bt[c][k0]) = make_uint4(w[0], w[1], w[2], w[3]);
            }
        }
    }
    __syncthreads();

    // ---- A fragments (u rows, bf16) straight from global into registers ----
    const int wid  = tid >> 6;
    const int lane = tid & 63;
    const int lr   = lane & 15;
    const int lk   = (lane >> 4) * 8;

    bf16x8 afrag[4][2];
    #pragma unroll
    for (int mt = 0; mt < 4; ++mt) {
        #pragma unroll
        for (int kb = 0; kb < 2; ++kb) {
            const int j = wid * 64 + mt * 16 + lr;
            const float4* s4 = reinterpret_cast<const float4*>(u + j * NBIT + kb * 32 + lk);
            float4 va = s4[0], vb = s4[1];
            union { bf16x8 v; unsigned int w[4]; } pk;
            pk.w[0] = (unsigned int)f2bf(va.x) | ((unsigned int)f2bf(va.y) << 16);
            pk.w[1] = (unsigned int)f2bf(va.z) | ((unsigned int)f2bf(va.w) << 16);
            pk.w[2] = (unsigned int)f2bf(vb.x) | ((unsigned int)f2bf(vb.y) << 16);
            pk.w[3] = (unsigned int)f2bf(vb.z) | ((unsigned int)f2bf(vb.w) << 16);
            afrag[mt][kb] = pk.v;
        }
    }
    int labR[4][4];
    #pragma unroll
    for (int mt = 0; mt < 4; ++mt)
        #pragma unroll
        for (int e = 0; e < 4; ++e)
            labR[mt][e] = labB[wid * 64 + mt * 16 + (lane >> 4) * 4 + e];

    // ---- MFMA + fused softplus epilogue ----
    float sum2 = 0.f;
    for (int nt = 0; nt < 8; ++nt) {
        if (t0 + nt * 16 >= (long)T_TOTAL) break;   // block-uniform; 200000 % 16 == 0
        const int col = nt * 16 + lr;
        union { bf16x8 v; uint4 q; } b0, b1;
        b0.q = *reinterpret_cast<const uint4*>(&Bt[col][lk]);
        b1.q = *reinterpret_cast<const uint4*>(&Bt[col][32 + lk]);
        const int labc = labT[col];
        #pragma unroll
        for (int mt = 0; mt < 4; ++mt) {
            f32x4 acc4 = {0.f, 0.f, 0.f, 0.f};
            acc4 = __builtin_amdgcn_mfma_f32_16x16x32_bf16(afrag[mt][0], b0.v, acc4, 0, 0, 0);
            acc4 = __builtin_amdgcn_mfma_f32_16x16x32_bf16(afrag[mt][1], b1.v, acc4, 0, 0, 0);
            #pragma unroll
            for (int e = 0; e < 4; ++e) {
                float ip = 0.5f * acc4[e];
                ip = fminf(fmaxf(ip, -100.f), 50.f);
                bool s = (labc == labR[mt][e]);
                float x = 1.f + (s ? -ip : ip);      // M = 1
                float e2 = exp2f(x * LOG2E);
                sum2 += log2f(1.f + e2);             // * ln2 applied at the end
            }
        }
    }
    for (int off = 32; off; off >>= 1) sum2 += __shfl_xor(sum2, off);
    if (lane == 0) wpart[wid] = sum2;
    __syncthreads();
    if (tid == 0) {
        double bs = (double)(wpart[0] + wpart[1] + wpart[2] + wpart[3]) * LN2;
        atomicAdd(acc, bs);
    }
}

// ---------------- kernel D: finalize loss ------------------------------------
__global__ void fin_kernel(const double* __restrict__ acc,
                           const float* __restrict__ quant,
                           float* __restrict__ out0) {
    out0[0] = (float)(acc[0] / ((double)BATCH * (double)T_TOTAL)
                      + 0.5 * ((double)quant[0] / (double)(BATCH * NBIT)));   // ETA=0.5
}

extern "C" void kernel_launch(void* const* d_in, const int* in_sizes, int n_in,
                              void* d_out, int out_size, void* d_ws, size_t ws_size,
                              hipStream_t stream) {
    const float* u   = (const float*)d_in[0];
    const float* y   = (const float*)d_in[1];
    const int*   ind = (const int*)d_in[2];
    const float* U   = (const float*)d_in[3];
    const float* Y   = (const float*)d_in[4];
    const float* C   = (const float*)d_in[5];
    float* out = (float*)d_out;

    double* acc   = (double*)d_ws;
    float*  quant = (float*)((char*)d_ws + 8);
    int*    lab   = (int*)((char*)d_ws + 64);

    prep_kernel<<<(BATCH * NCLASS + 255) / 256, 256, 0, stream>>>(y, lab, acc);
    dcc_kernel<<<1, 256, 0, stream>>>(u, C, lab, out + 1, quant);
    metric_kernel<<<NBLK, 256, 0, stream>>>(u, U, Y, ind, lab, acc);
    fin_kernel<<<1, 1, 0, stream>>>(acc, quant, out);
}